// Round 1
// baseline (6680.352 us; speedup 1.0000x reference)
//
#include <hip/hip_runtime.h>
#include <hip/hip_fp16.h>

typedef _Float16 half8 __attribute__((ext_vector_type(8)));
typedef float f32x4 __attribute__((ext_vector_type(4)));

#define B_ 256
#define SEQ_ 512
#define D_ 256
#define H_ 1024
#define C_ 10
#define S_ 511
#define KB_ 40      // K=1280 / 32
#define NPK_ 2048   // packed output cols per direction (g|i interleaved per 64)
#define NTF_ 128    // NPK/16 fine n-tiles

// ---- workspace byte offsets ----
#define WPK_HALVES (2*KB_*NTF_*512)                    // 5,242,880 halves
#define EMBH_OFF   (WPK_HALVES*2)                      // 10,485,760
#define EMBH_HALVES (SEQ_*D_)                          // 131,072
#define HPK_OFF    (EMBH_OFF + EMBH_HALVES*2)          // 10,747,904
#define HPK_PER_PAR (2*32*16*64*8)                     // 524,288 halves per parity (both dirs)
#define CST_OFF    (HPK_OFF + 2*HPK_PER_PAR*2)         // 12,845,056
#define CST_FLOATS (2*H_*B_)
#define HFIN_OFF   (CST_OFF + CST_FLOATS*4)            // 14,942,208
#define HFIN_FLOATS (2*B_*H_)
#define BIAS_OFF   (HFIN_OFF + HFIN_FLOATS*4)          // 17,039,360

// Pack fp32 weights -> fp16 in MFMA B-fragment-direct layout, emb -> fp16, biases -> packed.
// Packed col p: unit-block ub=p>>6 covers units [32ub,32ub+32), gate=(p>>5)&1, u=32ub+(p&31).
__global__ void convert_kernel(
    const float* __restrict__ emb,
    const float* __restrict__ Wgx_f, const float* __restrict__ Wgh_f, const float* __restrict__ bg_f,
    const float* __restrict__ Wix_f, const float* __restrict__ Wih_f, const float* __restrict__ bi_f,
    const float* __restrict__ Wgx_b, const float* __restrict__ Wgh_b, const float* __restrict__ bg_b,
    const float* __restrict__ Wix_b, const float* __restrict__ Wih_b, const float* __restrict__ bi_b,
    _Float16* __restrict__ Wpk, _Float16* __restrict__ embh, float* __restrict__ biaspk)
{
    int idx = blockIdx.x * 256 + threadIdx.x;
    if (idx < WPK_HALVES) {
        int j = idx & 7;
        int L = (idx >> 3) & 63;
        int rest = idx >> 9;
        int ntf = rest & (NTF_ - 1);
        int rest2 = rest >> 7;
        int kb = rest2 % KB_;
        int d  = rest2 / KB_;
        int k = kb*32 + ((L >> 4) << 3) + j;        // B-frag: lane quad gives k-octet
        int p = (ntf << 4) + (L & 15);              // lane low nibble gives col
        int gate = (p >> 5) & 1;
        int u = ((p >> 6) << 5) + (p & 31);
        float v;
        if (k < D_) {
            const float* W = d ? (gate ? Wix_b : Wgx_b) : (gate ? Wix_f : Wgx_f);
            v = W[k*H_ + u];
        } else {
            const float* W = d ? (gate ? Wih_b : Wgh_b) : (gate ? Wih_f : Wgh_f);
            v = W[(k - D_)*H_ + u];
        }
        Wpk[idx] = (_Float16)v;
    } else if (idx < WPK_HALVES + EMBH_HALVES) {
        int i2 = idx - WPK_HALVES;
        embh[i2] = (_Float16)emb[i2];
    } else if (idx < WPK_HALVES + EMBH_HALVES + 2*NPK_) {
        int i3 = idx - (WPK_HALVES + EMBH_HALVES);
        int d = i3 >> 11;
        int p = i3 & (NPK_ - 1);
        int gate = (p >> 5) & 1;
        int u = ((p >> 6) << 5) + (p & 31);
        const float* bsrc = d ? (gate ? bi_b : bg_b) : (gate ? bi_f : bg_f);
        biaspk[i3] = bsrc[u];
    }
}

// One timestep, both directions. Grid: 256 blocks = 2 dirs x 4 m-blocks x 32 unit-blocks.
// Block: 256 threads = 4 waves; 64x64 tile; K=1280 split 10 k-blocks per wave; LDS reduce.
__global__ __launch_bounds__(256, 1) void step_kernel(
    const int* __restrict__ x, const _Float16* __restrict__ embh,
    const _Float16* __restrict__ Wpk, const float* __restrict__ biaspk,
    const _Float16* __restrict__ hrd_base, _Float16* __restrict__ hwr_base,
    float* __restrict__ cstate, float* __restrict__ hfinal,
    int t, int is_first, int is_last)
{
    __shared__ float lds[4][64][65];
    int dir   = blockIdx.x >> 7;
    int bid   = blockIdx.x & 127;
    int mtblk = bid >> 5;
    int ntb   = bid & 31;
    int w    = threadIdx.x >> 6;
    int lane = threadIdx.x & 63;
    int q    = lane >> 4;
    int c16  = lane & 15;
    int t_eff = dir ? (S_ - 1 - t) : t;

    const _Float16* Wd  = Wpk + (size_t)dir * (KB_*NTF_*512);
    const _Float16* hrd = hrd_base + dir * (32*16*64*8);
    _Float16*       hwr = hwr_base + dir * (32*16*64*8);

    int xr[4];
    #pragma unroll
    for (int mt = 0; mt < 4; ++mt) {
        int m = mtblk*64 + mt*16 + c16;
        xr[mt] = x[m*SEQ_ + t_eff];
    }

    f32x4 acc[4][4];
    #pragma unroll
    for (int a = 0; a < 4; ++a) {
        #pragma unroll
        for (int b = 0; b < 4; ++b) {
            acc[a][b][0] = 0.f; acc[a][b][1] = 0.f; acc[a][b][2] = 0.f; acc[a][b][3] = 0.f;
        }
    }

    int kb0 = w * 10;
    #pragma unroll
    for (int kk = 0; kk < 10; ++kk) {
        int kb = kb0 + kk;
        half8 a[4];
        if (kb < 8) {                       // x part: gather from fp16 emb rows
            #pragma unroll
            for (int mt = 0; mt < 4; ++mt)
                a[mt] = *(const half8*)(embh + xr[mt]*D_ + kb*32 + q*8);
        } else if (is_first) {              // h0 = 0
            #pragma unroll
            for (int mt = 0; mt < 4; ++mt) {
                #pragma unroll
                for (int e = 0; e < 8; ++e) a[mt][e] = (_Float16)0.f;
            }
        } else {                            // h part: A-fragment-direct layout
            int kb2 = kb - 8;
            #pragma unroll
            for (int mt = 0; mt < 4; ++mt)
                a[mt] = *(const half8*)(hrd + ((kb2*16 + (mtblk*4 + mt))*64 + lane)*8);
        }
        half8 bfr[4];
        #pragma unroll
        for (int nt = 0; nt < 4; ++nt)
            bfr[nt] = *(const half8*)(Wd + (((size_t)kb*NTF_ + (ntb*4 + nt))*64 + lane)*8);
        #pragma unroll
        for (int mt = 0; mt < 4; ++mt) {
            #pragma unroll
            for (int nt = 0; nt < 4; ++nt)
                acc[mt][nt] = __builtin_amdgcn_mfma_f32_16x16x32_f16(a[mt], bfr[nt], acc[mt][nt], 0, 0, 0);
        }
    }

    // K-split partials -> LDS
    #pragma unroll
    for (int mt = 0; mt < 4; ++mt) {
        #pragma unroll
        for (int nt = 0; nt < 4; ++nt) {
            #pragma unroll
            for (int r = 0; r < 4; ++r)
                lds[w][mt*16 + q*4 + r][nt*16 + c16] = acc[mt][nt][r];
        }
    }
    __syncthreads();

    // Epilogue: wave w owns rows [16w,16w+16). nt in {0,1}=g cols, +2 = i cols (same unit).
    #pragma unroll
    for (int nt = 0; nt < 2; ++nt) {
        #pragma unroll
        for (int r = 0; r < 4; ++r) {
            int ml = 16*w + q*4 + r;
            int cg = nt*16 + c16;
            int ci = (nt + 2)*16 + c16;
            float zg = lds[0][ml][cg] + lds[1][ml][cg] + lds[2][ml][cg] + lds[3][ml][cg];
            float zi = lds[0][ml][ci] + lds[1][ml][ci] + lds[2][ml][ci] + lds[3][ml][ci];
            zg += biaspk[dir*NPK_ + ntb*64 + cg];
            zi += biaspk[dir*NPK_ + ntb*64 + ci];
            int u = ntb*32 + nt*16 + c16;
            int m = mtblk*64 + ml;
            float g  = tanhf(zg);
            float ii = 1.f / (1.f + expf(-zi));
            float cp = is_first ? 0.f : cstate[dir*(H_*B_) + u*B_ + m];
            float cn = ii * (g + cp);
            cstate[dir*(H_*B_) + u*B_ + m] = cn;
            float h = tanhf(cn) * ii;
            // write h into next step's A-fragment-direct layout (k = 256+u)
            int kb2 = u >> 5, k5 = u & 31, qd = k5 >> 3, jj = k5 & 7;
            int mt2 = m >> 4, ln2 = (m & 15) + (qd << 4);
            hwr[((kb2*16 + mt2)*64 + ln2)*8 + jj] = (_Float16)h;
            if (is_last) hfinal[dir*(B_*H_) + m*H_ + u] = h;
        }
    }
}

// out[b][c] = [hf|hb] @ Wp + bp
__global__ void proj_kernel(const float* __restrict__ hfinal,
                            const float* __restrict__ Wp, const float* __restrict__ bp,
                            float* __restrict__ out)
{
    int b = blockIdx.x;
    int lane = threadIdx.x;
    float s[C_];
    #pragma unroll
    for (int c = 0; c < C_; ++c) s[c] = 0.f;
    for (int j = lane; j < 2*H_; j += 64) {
        float hv = (j < H_) ? hfinal[b*H_ + j] : hfinal[B_*H_ + b*H_ + (j - H_)];
        const float* wr = Wp + j*C_;
        #pragma unroll
        for (int c = 0; c < C_; ++c) s[c] += hv * wr[c];
    }
    #pragma unroll
    for (int off = 32; off > 0; off >>= 1) {
        #pragma unroll
        for (int c = 0; c < C_; ++c) s[c] += __shfl_down(s[c], off);
    }
    if (lane == 0) {
        #pragma unroll
        for (int c = 0; c < C_; ++c) out[b*C_ + c] = s[c] + bp[c];
    }
}

extern "C" void kernel_launch(void* const* d_in, const int* in_sizes, int n_in,
                              void* d_out, int out_size, void* d_ws, size_t ws_size,
                              hipStream_t stream)
{
    const int*   x     = (const int*)d_in[0];
    const float* emb   = (const float*)d_in[1];
    const float* Wgx_f = (const float*)d_in[2];
    const float* Wgh_f = (const float*)d_in[3];
    const float* bg_f  = (const float*)d_in[4];
    const float* Wix_f = (const float*)d_in[5];
    const float* Wih_f = (const float*)d_in[6];
    const float* bi_f  = (const float*)d_in[7];
    const float* Wgx_b = (const float*)d_in[8];
    const float* Wgh_b = (const float*)d_in[9];
    const float* bg_b  = (const float*)d_in[10];
    const float* Wix_b = (const float*)d_in[11];
    const float* Wih_b = (const float*)d_in[12];
    const float* bi_b  = (const float*)d_in[13];
    const float* Wp    = (const float*)d_in[14];
    const float* bp    = (const float*)d_in[15];
    float* out = (float*)d_out;

    char* ws = (char*)d_ws;
    _Float16* Wpk    = (_Float16*)(ws + 0);
    _Float16* embh   = (_Float16*)(ws + EMBH_OFF);
    _Float16* hpk    = (_Float16*)(ws + HPK_OFF);
    float*    cstate = (float*)(ws + CST_OFF);
    float*    hfinal = (float*)(ws + HFIN_OFF);
    float*    biaspk = (float*)(ws + BIAS_OFF);

    int total = WPK_HALVES + EMBH_HALVES + 2*NPK_;
    convert_kernel<<<(total + 255)/256, 256, 0, stream>>>(
        emb, Wgx_f, Wgh_f, bg_f, Wix_f, Wih_f, bi_f,
        Wgx_b, Wgh_b, bg_b, Wix_b, Wih_b, bi_b, Wpk, embh, biaspk);

    for (int t = 0; t < S_; ++t) {
        const _Float16* hrd = hpk + (size_t)(t & 1) * HPK_PER_PAR;
        _Float16*       hwr = hpk + (size_t)((t & 1) ^ 1) * HPK_PER_PAR;
        step_kernel<<<256, 256, 0, stream>>>(x, embh, Wpk, biaspk, hrd, hwr,
                                             cstate, hfinal, t, t == 0 ? 1 : 0, t == S_ - 1 ? 1 : 0);
    }

    proj_kernel<<<B_, 64, 0, stream>>>(hfinal, Wp, bp, out);
}